// Round 4
// baseline (306.077 us; speedup 1.0000x reference)
//
#include <hip/hip_runtime.h>

typedef unsigned short u16;
typedef unsigned int u32;
typedef __bf16 bf16x8 __attribute__((ext_vector_type(8)));
typedef float f32x4 __attribute__((ext_vector_type(4)));

__device__ __forceinline__ u16 f2bf(float f) {
  union { float f; u32 u; } c; c.f = f;
  return (u16)((c.u + 0x7fffu + ((c.u >> 16) & 1u)) >> 16);  // RNE
}
__device__ __forceinline__ float2 upk2(u32 v) {
  union { u32 u; float f; } a, b; a.u = v << 16; b.u = v & 0xffff0000u;
  return make_float2(a.f, b.f);
}
__device__ __forceinline__ u32 pk2(float x, float y) {
  return (u32)f2bf(x) | ((u32)f2bf(y) << 16);
}

// ---------------- fp32 -> bf16 cast ----------------
__global__ __launch_bounds__(256) void k_cast(const float4* __restrict__ in,
                                              uint2* __restrict__ out, int n4) {
  int i = blockIdx.x * 256 + threadIdx.x;
  if (i < n4) {
    float4 v = in[i];
    out[i] = make_uint2(pk2(v.x, v.y), pk2(v.z, v.w));
  }
}

// ---------------- CSR build ----------------
__global__ __launch_bounds__(256) void k_hist(const int* __restrict__ dst,
                                              int* __restrict__ counts, int E) {
  int e = blockIdx.x * 256 + threadIdx.x;
  if (e < E) atomicAdd(&counts[dst[e]], 1);
}

__global__ __launch_bounds__(256) void k_scan1(const int* __restrict__ counts,
                                               int* __restrict__ excl,
                                               int* __restrict__ partials, int n) {
  __shared__ int sh[256];
  int b = blockIdx.x, t = threadIdx.x;
  int base = b * 1024 + t * 4;
  int v[4];
#pragma unroll
  for (int j = 0; j < 4; ++j) { int i = base + j; v[j] = (i < n) ? counts[i] : 0; }
  int tot = v[0] + v[1] + v[2] + v[3];
  sh[t] = tot; __syncthreads();
  for (int off = 1; off < 256; off <<= 1) {
    int x = (t >= off) ? sh[t - off] : 0;
    __syncthreads();
    sh[t] += x;
    __syncthreads();
  }
  int run = sh[t] - tot;  // exclusive over threads in block
#pragma unroll
  for (int j = 0; j < 4; ++j) {
    int i = base + j;
    if (i < n) excl[i] = run;
    run += v[j];
  }
  if (t == 255) partials[b] = sh[255];
}

__global__ __launch_bounds__(128) void k_scan2(int* __restrict__ partials, int nb) {
  __shared__ int sh[128];
  int t = threadIdx.x;
  int v = (t < nb) ? partials[t] : 0;
  sh[t] = v; __syncthreads();
  for (int off = 1; off < 128; off <<= 1) {
    int x = (t >= off) ? sh[t - off] : 0;
    __syncthreads();
    sh[t] += x;
    __syncthreads();
  }
  if (t < nb) partials[t] = sh[t] - v;  // exclusive
}

__global__ __launch_bounds__(256) void k_scan3(int* __restrict__ rowstart,
                                               int* __restrict__ cursor,
                                               const int* __restrict__ partials,
                                               int n, int E) {
  int i = blockIdx.x * 256 + threadIdx.x;
  if (i < n) {
    int v = rowstart[i] + partials[i >> 10];
    rowstart[i] = v;
    cursor[i] = v;
  }
  if (i == 0) rowstart[n] = E;
}

__global__ __launch_bounds__(256) void k_fill(const int* __restrict__ src,
                                              const int* __restrict__ dst,
                                              int* __restrict__ cursor,
                                              int* __restrict__ edge_src, int E) {
  int e = blockIdx.x * 256 + threadIdx.x;
  if (e < E) {
    int d = dst[e];
    int pos = atomicAdd(&cursor[d], 1);
    edge_src[pos] = src[e];
  }
}

// ---------------- weight transpose+cast: wT[w][n][k] = bf16(w[k][n]) ----------------
__global__ __launch_bounds__(256) void k_tr(const float* __restrict__ w0,
                                            const float* __restrict__ w1,
                                            const float* __restrict__ w2,
                                            const float* __restrict__ w3,
                                            u16* __restrict__ wT) {
  int id = blockIdx.x * 256 + threadIdx.x;  // 0..65535
  int w = id >> 14, rem = id & 16383;
  int nn = rem >> 7, kk = rem & 127;
  const float* s = (w == 0) ? w0 : (w == 1) ? w1 : (w == 2) ? w2 : w3;
  wT[id] = f2bf(s[kk * 128 + nn]);
}

// ---------------- fused layer: agg (gather, f32 acc) -> LDS tile -> 2-GEMM MLP ----------------
// LDS layout: 16B chunks, chunk c of row r stored at elem offset r*128 + ((c ^ (r&15))*8)
template <bool HEAD>
__global__ __launch_bounds__(256) void k_fused(const u32* __restrict__ in,   // [N][64] bf16x2
                                               const int* __restrict__ rowstart,
                                               const int* __restrict__ edge_src,
                                               const u16* __restrict__ wAT,  // [128n][128k] bf16
                                               const float* __restrict__ bA,
                                               const u16* __restrict__ wBT,
                                               const float* __restrict__ bB,
                                               const float* __restrict__ wo,  // [128] (HEAD)
                                               const float* __restrict__ bo,  // [1]   (HEAD)
                                               void* __restrict__ outp, int N) {
  __shared__ u16 lA[64 * 128];    // agg tile / h1 tile / out tile
  __shared__ u16 lW[128 * 128];   // weight tile (transposed: row n, k contiguous)
  const int tid = threadIdx.x;
  const int wave = tid >> 6, lane = tid & 63;
  const int base = blockIdx.x * 64;

  // stage W = wAT first so these loads are in flight during the gather phase
#pragma unroll
  for (int it = 0; it < 8; ++it) {
    int id = it * 256 + tid;            // 2048 chunks
    int row = id >> 4, c = id & 15;
    uint4 v = *(const uint4*)&wAT[row * 128 + c * 8];
    *(uint4*)&lW[row * 128 + ((c ^ (row & 15)) << 3)] = v;
  }

  // ---- gather phase: wave w owns rows w*16..w*16+15; pair (i, i+8) for 16 in-flight loads ----
  const u32* __restrict__ col = in + lane;
  const int ldsw = ((lane >> 2) /*chunk*/);
  for (int i = 0; i < 8; ++i) {
    int rA = wave * 16 + i, rB = rA + 8;
    int nodeA = __builtin_amdgcn_readfirstlane(base + rA);
    int nodeB = __builtin_amdgcn_readfirstlane(base + rB);
    bool vA = nodeA < N, vB = nodeB < N;
    float2 accA = make_float2(0.f, 0.f), accB = make_float2(0.f, 0.f);
    int a0 = 0, a1 = 0, b0 = 0, b1 = 0;
    if (vA) { a0 = rowstart[nodeA]; a1 = rowstart[nodeA + 1]; accA = upk2(col[(size_t)nodeA * 64]); }
    if (vB) { b0 = rowstart[nodeB]; b1 = rowstart[nodeB + 1]; accB = upk2(col[(size_t)nodeB * 64]); }
    int ea = a0, eb = b0;
    // paired batches: 16 independent loads in flight
    while (ea < a1 && eb < b1) {
      int ia[8], ib[8]; float wa[8], wb[8]; u32 va[8], vb[8];
#pragma unroll
      for (int j = 0; j < 8; ++j) {
        int ej = ea + j; int c = (ej < a1) ? ej : (a1 - 1);
        ia[j] = edge_src[c]; wa[j] = (ej < a1) ? 1.f : 0.f;
        int fj = eb + j; int d = (fj < b1) ? fj : (b1 - 1);
        ib[j] = edge_src[d]; wb[j] = (fj < b1) ? 1.f : 0.f;
      }
#pragma unroll
      for (int j = 0; j < 8; ++j) { va[j] = col[(size_t)ia[j] * 64]; vb[j] = col[(size_t)ib[j] * 64]; }
#pragma unroll
      for (int j = 0; j < 8; ++j) {
        float2 p = upk2(va[j]);
        accA.x = fmaf(wa[j], p.x, accA.x); accA.y = fmaf(wa[j], p.y, accA.y);
        float2 q = upk2(vb[j]);
        accB.x = fmaf(wb[j], q.x, accB.x); accB.y = fmaf(wb[j], q.y, accB.y);
      }
      ea += 8; eb += 8;
    }
    // drain tails (at most one side runs)
    while (ea < a1) {
      int ia[8]; float wa[8]; u32 va[8];
#pragma unroll
      for (int j = 0; j < 8; ++j) {
        int ej = ea + j; int c = (ej < a1) ? ej : (a1 - 1);
        ia[j] = edge_src[c]; wa[j] = (ej < a1) ? 1.f : 0.f;
      }
#pragma unroll
      for (int j = 0; j < 8; ++j) va[j] = col[(size_t)ia[j] * 64];
#pragma unroll
      for (int j = 0; j < 8; ++j) {
        float2 p = upk2(va[j]);
        accA.x = fmaf(wa[j], p.x, accA.x); accA.y = fmaf(wa[j], p.y, accA.y);
      }
      ea += 8;
    }
    while (eb < b1) {
      int ib[8]; float wb[8]; u32 vb[8];
#pragma unroll
      for (int j = 0; j < 8; ++j) {
        int fj = eb + j; int d = (fj < b1) ? fj : (b1 - 1);
        ib[j] = edge_src[d]; wb[j] = (fj < b1) ? 1.f : 0.f;
      }
#pragma unroll
      for (int j = 0; j < 8; ++j) vb[j] = col[(size_t)ib[j] * 64];
#pragma unroll
      for (int j = 0; j < 8; ++j) {
        float2 q = upk2(vb[j]);
        accB.x = fmaf(wb[j], q.x, accB.x); accB.y = fmaf(wb[j], q.y, accB.y);
      }
      eb += 8;
    }
    // write swizzled bf16 rows into lA (u32 = 2 elems; chunk = lane>>2, pos = (lane&3)*2)
    if (vA)
      *(u32*)&lA[rA * 128 + (((ldsw ^ (rA & 15)) << 3) | ((lane & 3) << 1))] = pk2(accA.x, accA.y);
    if (vB)
      *(u32*)&lA[rB * 128 + (((ldsw ^ (rB & 15)) << 3) | ((lane & 3) << 1))] = pk2(accB.x, accB.y);
  }
  __syncthreads();

  const int m16 = lane & 15, quad = lane >> 4;
  const int mrow = wave * 16 + m16;

  // ---- GEMM1: h1 = relu(A @ wA + bA) ----
  bf16x8 aF[4];
#pragma unroll
  for (int ks = 0; ks < 4; ++ks)
    aF[ks] = *(const bf16x8*)&lA[mrow * 128 + (((ks * 4 + quad) ^ m16) << 3)];
  f32x4 acc[8];
#pragma unroll
  for (int t = 0; t < 8; ++t) acc[t] = (f32x4){0.f, 0.f, 0.f, 0.f};
#pragma unroll
  for (int t = 0; t < 8; ++t) {
    int nrow = t * 16 + m16;
#pragma unroll
    for (int ks = 0; ks < 4; ++ks) {
      bf16x8 bF = *(const bf16x8*)&lW[nrow * 128 + (((ks * 4 + quad) ^ m16) << 3)];
      acc[t] = __builtin_amdgcn_mfma_f32_16x16x32_bf16(aF[ks], bF, acc[t], 0, 0, 0);
    }
  }
  __syncthreads();  // all GEMM1 LDS reads complete before overwriting lA/lW

  // epilogue 1: write h1 (bf16) into lA (own wave's rows only)
#pragma unroll
  for (int t = 0; t < 8; ++t) {
    int n = t * 16 + m16;
    float bias = bA[n];
#pragma unroll
    for (int r = 0; r < 4; ++r) {
      int rloc = quad * 4 + r;                 // row within wave's 16 (== absrow & 15)
      int absrow = wave * 16 + rloc;
      float v = acc[t][r] + bias;
      v = v > 0.f ? v : 0.f;
      lA[absrow * 128 + ((((n >> 3) ^ rloc) << 3) | (n & 7))] = f2bf(v);
    }
  }
  // restage W = wBT
#pragma unroll
  for (int it = 0; it < 8; ++it) {
    int id = it * 256 + tid;
    int row = id >> 4, c = id & 15;
    uint4 v = *(const uint4*)&wBT[row * 128 + c * 8];
    *(uint4*)&lW[row * 128 + ((c ^ (row & 15)) << 3)] = v;
  }
  __syncthreads();

  // ---- GEMM2: h2 = h1 @ wB + bB ----
#pragma unroll
  for (int ks = 0; ks < 4; ++ks)
    aF[ks] = *(const bf16x8*)&lA[mrow * 128 + (((ks * 4 + quad) ^ m16) << 3)];
#pragma unroll
  for (int t = 0; t < 8; ++t) acc[t] = (f32x4){0.f, 0.f, 0.f, 0.f};
#pragma unroll
  for (int t = 0; t < 8; ++t) {
    int nrow = t * 16 + m16;
#pragma unroll
    for (int ks = 0; ks < 4; ++ks) {
      bf16x8 bF = *(const bf16x8*)&lW[nrow * 128 + (((ks * 4 + quad) ^ m16) << 3)];
      acc[t] = __builtin_amdgcn_mfma_f32_16x16x32_bf16(aF[ks], bF, acc[t], 0, 0, 0);
    }
  }
  // epilogue 2: write result (bf16) into lA (own rows; own aF already consumed)
#pragma unroll
  for (int t = 0; t < 8; ++t) {
    int n = t * 16 + m16;
    float bias = bB[n];
#pragma unroll
    for (int r = 0; r < 4; ++r) {
      int rloc = quad * 4 + r;
      int absrow = wave * 16 + rloc;
      float v = acc[t][r] + bias;
      lA[absrow * 128 + ((((n >> 3) ^ rloc) << 3) | (n & 7))] = f2bf(v);
    }
  }
  __syncthreads();  // cross-wave readback below

  if (!HEAD) {
    u16* out = (u16*)outp;
    // coalesced tile store: 64 rows x 256B
#pragma unroll
    for (int it = 0; it < 4; ++it) {
      int id = it * 256 + tid;
      int row = id >> 4, c = id & 15;
      if (base + row < N) {
        uint4 v = *(const uint4*)&lA[row * 128 + ((c ^ (row & 15)) << 3)];
        *(uint4*)&out[(base + row) * 128 + c * 8] = v;
      }
    }
  } else {
    float* out = (float*)outp;
    // head: out[row] = h2b[row,:] . wo + bo ; 4 threads per row
    int row = tid >> 2, qh = tid & 3;
    float s = 0.f;
#pragma unroll
    for (int j = 0; j < 4; ++j) {
      int c = qh * 4 + j;
      uint4 v = *(const uint4*)&lA[row * 128 + ((c ^ (row & 15)) << 3)];
      const float* w = &wo[c * 8];
      float2 p;
      p = upk2(v.x); s += p.x * w[0] + p.y * w[1];
      p = upk2(v.y); s += p.x * w[2] + p.y * w[3];
      p = upk2(v.z); s += p.x * w[4] + p.y * w[5];
      p = upk2(v.w); s += p.x * w[6] + p.y * w[7];
    }
    s += __shfl_xor(s, 1, 64);
    s += __shfl_xor(s, 2, 64);
    if (qh == 0 && base + row < N) {
      out[base + row] = s + bo[0];
    }
  }
}

extern "C" void kernel_launch(void* const* d_in, const int* in_sizes, int n_in,
                              void* d_out, int out_size, void* d_ws, size_t ws_size,
                              hipStream_t stream) {
  const float* x = (const float*)d_in[0];
  const int* ei = (const int*)d_in[1];
  const int E = in_sizes[1] / 2;
  const int N = in_sizes[0] / 128;
  const int* srcI = ei;
  const int* dstI = ei + E;
  const float* w1a = (const float*)d_in[2];
  const float* b1a = (const float*)d_in[3];
  const float* w1b = (const float*)d_in[4];
  const float* b1b = (const float*)d_in[5];
  const float* w2a = (const float*)d_in[6];
  const float* b2a = (const float*)d_in[7];
  const float* w2b = (const float*)d_in[8];
  const float* b2b = (const float*)d_in[9];
  const float* wo = (const float*)d_in[10];
  const float* bo = (const float*)d_in[11];

  char* ws = (char*)d_ws;
  size_t off = 0;
  auto nx = [&](size_t bytes) {
    size_t o = off;
    off += (bytes + 511) & ~(size_t)511;
    return o;
  };
  int* cursor   = (int*)(ws + nx((size_t)N * 4));        // counts, then fill cursor
  int* rowstart = (int*)(ws + nx((size_t)(N + 1) * 4));
  int* partials = (int*)(ws + nx(4096));
  int* edge_src = (int*)(ws + nx((size_t)E * 4));
  u16* wT       = (u16*)(ws + nx((size_t)4 * 16384 * 2));
  u16* xb       = (u16*)(ws + nx((size_t)N * 128 * 2));  // bf16 x
  u16* bufB     = (u16*)(ws + nx((size_t)N * 128 * 2));  // layer-1 output

  const int nb = (N + 1023) >> 10;  // scan chunks

  hipMemsetAsync(cursor, 0, (size_t)N * 4, stream);
  k_hist<<<(E + 255) / 256, 256, 0, stream>>>(dstI, cursor, E);
  k_scan1<<<nb, 256, 0, stream>>>(cursor, rowstart, partials, N);
  k_scan2<<<1, 128, 0, stream>>>(partials, nb);
  k_scan3<<<(N + 255) / 256, 256, 0, stream>>>(rowstart, cursor, partials, N, E);
  k_fill<<<(E + 255) / 256, 256, 0, stream>>>(srcI, dstI, cursor, edge_src, E);
  k_tr<<<256, 256, 0, stream>>>(w1a, w1b, w2a, w2b, wT);

  const int n4 = N * 32;  // N*128/4
  k_cast<<<(n4 + 255) / 256, 256, 0, stream>>>((const float4*)x, (uint2*)xb, n4);

  const int nblk = (N + 63) / 64;
  k_fused<false><<<nblk, 256, 0, stream>>>((const u32*)xb, rowstart, edge_src,
                                           wT, b1a, wT + 16384, b1b,
                                           nullptr, nullptr, bufB, N);
  k_fused<true><<<nblk, 256, 0, stream>>>((const u32*)bufB, rowstart, edge_src,
                                          wT + 32768, b2a, wT + 49152, b2b,
                                          wo, bo, d_out, N);
}

// Round 5
// 271.014 us; speedup vs baseline: 1.1294x; 1.1294x over previous
//
#include <hip/hip_runtime.h>

typedef unsigned short u16;
typedef unsigned int u32;
typedef __bf16 bf16x8 __attribute__((ext_vector_type(8)));
typedef float f32x4 __attribute__((ext_vector_type(4)));

__device__ __forceinline__ u16 f2bf(float f) {
  union { float f; u32 u; } c; c.f = f;
  return (u16)((c.u + 0x7fffu + ((c.u >> 16) & 1u)) >> 16);  // RNE
}
__device__ __forceinline__ float2 upk2(u32 v) {
  union { u32 u; float f; } a, b; a.u = v << 16; b.u = v & 0xffff0000u;
  return make_float2(a.f, b.f);
}
__device__ __forceinline__ u32 pk2(float x, float y) {
  return (u32)f2bf(x) | ((u32)f2bf(y) << 16);
}

// ---------------- prep: cast (fp32->bf16) + hist + weight transpose, fused by block range ------
__global__ __launch_bounds__(256) void k_prep(const float4* __restrict__ x4,
                                              uint2* __restrict__ xb,
                                              int n4, int castBlocks,
                                              const int* __restrict__ dst,
                                              int* __restrict__ counts,
                                              int E, int histBlocks,
                                              const float* __restrict__ w0,
                                              const float* __restrict__ w1,
                                              const float* __restrict__ w2,
                                              const float* __restrict__ w3,
                                              u16* __restrict__ wT) {
  int b = blockIdx.x, t = threadIdx.x;
  if (b < castBlocks) {
    int i = b * 256 + t;
    if (i < n4) {
      float4 v = x4[i];
      xb[i] = make_uint2(pk2(v.x, v.y), pk2(v.z, v.w));
    }
  } else if (b < castBlocks + histBlocks) {
    int e = (b - castBlocks) * 256 + t;
    if (e < E) atomicAdd(&counts[dst[e]], 1);
  } else {
    int id = (b - castBlocks - histBlocks) * 256 + t;  // 0..65535
    int w = id >> 14, rem = id & 16383;
    int nn = rem >> 7, kk = rem & 127;
    const float* s = (w == 0) ? w0 : (w == 1) ? w1 : (w == 2) ? w2 : w3;
    wT[id] = f2bf(s[kk * 128 + nn]);
  }
}

// ---------------- CSR scan ----------------
__global__ __launch_bounds__(256) void k_scan1(const int* __restrict__ counts,
                                               int* __restrict__ excl,
                                               int* __restrict__ partials, int n) {
  __shared__ int sh[256];
  int b = blockIdx.x, t = threadIdx.x;
  int base = b * 1024 + t * 4;
  int v[4];
#pragma unroll
  for (int j = 0; j < 4; ++j) { int i = base + j; v[j] = (i < n) ? counts[i] : 0; }
  int tot = v[0] + v[1] + v[2] + v[3];
  sh[t] = tot; __syncthreads();
  for (int off = 1; off < 256; off <<= 1) {
    int x = (t >= off) ? sh[t - off] : 0;
    __syncthreads();
    sh[t] += x;
    __syncthreads();
  }
  int run = sh[t] - tot;  // exclusive over threads in block
#pragma unroll
  for (int j = 0; j < 4; ++j) {
    int i = base + j;
    if (i < n) excl[i] = run;
    run += v[j];
  }
  if (t == 255) partials[b] = sh[255];
}

// scan of partials (redundant per block) + apply + cursor init; merges old scan2+scan3
__global__ __launch_bounds__(256) void k_scan23(int* __restrict__ rowstart,
                                                int* __restrict__ cursor,
                                                const int* __restrict__ partials,
                                                int n, int E, int nb) {
  __shared__ int sh[128];
  int t = threadIdx.x;
  int own = 0;
  if (t < 128) { own = (t < nb) ? partials[t] : 0; sh[t] = own; }
  __syncthreads();
  for (int off = 1; off < 128; off <<= 1) {
    int x = (t >= off && t < 128) ? sh[t - off] : 0;
    __syncthreads();
    if (t < 128) sh[t] += x;
    __syncthreads();
  }
  if (t < 128) sh[t] -= own;  // exclusive
  __syncthreads();
  int i = blockIdx.x * 256 + t;
  if (i < n) {
    int v = rowstart[i] + sh[i >> 10];
    rowstart[i] = v;
    cursor[i] = v;
  }
  if (i == 0) rowstart[n] = E;
}

__global__ __launch_bounds__(256) void k_fill(const int* __restrict__ src,
                                              const int* __restrict__ dst,
                                              int* __restrict__ cursor,
                                              int* __restrict__ edge_src, int E) {
  int e = blockIdx.x * 256 + threadIdx.x;
  if (e < E) {
    int d = dst[e];
    int pos = atomicAdd(&cursor[d], 1);
    edge_src[pos] = src[e];
  }
}

// ---------------- aggregation: out[n] = in[n] + sum_{s in nbr(n)} in[s] (bf16 io, f32 acc) --------
// One wave per node PAIR (2p, 2p+1): 16 independent row-loads in flight (latency hiding),
// wave-uniform node -> s_load indices + saddr-form row gathers. Contiguous pair => b0 == a1.
__global__ __launch_bounds__(256) void k_agg(const u32* __restrict__ in,
                                             u32* __restrict__ out,
                                             const int* __restrict__ rowstart,
                                             const int* __restrict__ edge_src, int N) {
  int pair = blockIdx.x * 4 + (threadIdx.x >> 6);
  int lane = threadIdx.x & 63;
  int nodeA = __builtin_amdgcn_readfirstlane(pair * 2);
  if (nodeA >= N) return;
  int nodeB = nodeA + 1;
  bool vB = nodeB < N;
  const u32* __restrict__ col = in + lane;
  float2 accA = upk2(col[(size_t)nodeA * 64]);
  float2 accB = vB ? upk2(col[(size_t)nodeB * 64]) : make_float2(0.f, 0.f);
  int a0 = rowstart[nodeA], a1 = rowstart[nodeA + 1];
  int b0 = a1, b1 = vB ? rowstart[nodeB + 1] : a1;
  int ea = a0, eb = b0;
  while (ea < a1 && eb < b1) {
    int ia[8], ib[8]; float wa[8], wb[8]; u32 va[8], vb8[8];
#pragma unroll
    for (int j = 0; j < 8; ++j) {
      int ej = ea + j; int c = (ej < a1) ? ej : (a1 - 1);
      ia[j] = edge_src[c]; wa[j] = (ej < a1) ? 1.f : 0.f;
      int fj = eb + j; int d = (fj < b1) ? fj : (b1 - 1);
      ib[j] = edge_src[d]; wb[j] = (fj < b1) ? 1.f : 0.f;
    }
#pragma unroll
    for (int j = 0; j < 8; ++j) { va[j] = col[(size_t)ia[j] * 64]; vb8[j] = col[(size_t)ib[j] * 64]; }
#pragma unroll
    for (int j = 0; j < 8; ++j) {
      float2 p = upk2(va[j]);
      accA.x = fmaf(wa[j], p.x, accA.x); accA.y = fmaf(wa[j], p.y, accA.y);
      float2 q = upk2(vb8[j]);
      accB.x = fmaf(wb[j], q.x, accB.x); accB.y = fmaf(wb[j], q.y, accB.y);
    }
    ea += 8; eb += 8;
  }
  while (ea < a1) {
    int ia[8]; float wa[8]; u32 va[8];
#pragma unroll
    for (int j = 0; j < 8; ++j) {
      int ej = ea + j; int c = (ej < a1) ? ej : (a1 - 1);
      ia[j] = edge_src[c]; wa[j] = (ej < a1) ? 1.f : 0.f;
    }
#pragma unroll
    for (int j = 0; j < 8; ++j) va[j] = col[(size_t)ia[j] * 64];
#pragma unroll
    for (int j = 0; j < 8; ++j) {
      float2 p = upk2(va[j]);
      accA.x = fmaf(wa[j], p.x, accA.x); accA.y = fmaf(wa[j], p.y, accA.y);
    }
    ea += 8;
  }
  while (eb < b1) {
    int ib[8]; float wb[8]; u32 vb8[8];
#pragma unroll
    for (int j = 0; j < 8; ++j) {
      int fj = eb + j; int d = (fj < b1) ? fj : (b1 - 1);
      ib[j] = edge_src[d]; wb[j] = (fj < b1) ? 1.f : 0.f;
    }
#pragma unroll
    for (int j = 0; j < 8; ++j) vb8[j] = col[(size_t)ib[j] * 64];
#pragma unroll
    for (int j = 0; j < 8; ++j) {
      float2 q = upk2(vb8[j]);
      accB.x = fmaf(wb[j], q.x, accB.x); accB.y = fmaf(wb[j], q.y, accB.y);
    }
    eb += 8;
  }
  out[(size_t)nodeA * 64 + lane] = pk2(accA.x, accA.y);
  if (vB) out[(size_t)nodeB * 64 + lane] = pk2(accB.x, accB.y);
}

// ---------------- fused MLP: out = relu(in@wA+bA)@wB + bB  (+ optional head dot) ----------------
// LDS layout: 16B chunks, chunk c of row r stored at r*128 + ((c ^ (r&15))*8)
template <bool HEAD>
__global__ __launch_bounds__(256) void k_mlp(const u16* __restrict__ in,   // [N,128] bf16
                                             const u16* __restrict__ wAT,  // [128n][128k] bf16
                                             const float* __restrict__ bA,
                                             const u16* __restrict__ wBT,
                                             const float* __restrict__ bB,
                                             const float* __restrict__ wo,  // [128] (HEAD)
                                             const float* __restrict__ bo,  // [1]   (HEAD)
                                             void* __restrict__ outp, int N) {
  __shared__ u16 lA[64 * 128];    // A tile / h1 tile / out tile (rows are wave-private)
  __shared__ u16 lW[128 * 128];   // weight tile (transposed: row n, k contiguous)
  const int tid = threadIdx.x;
  const int wave = tid >> 6, lane = tid & 63;
  const int base = blockIdx.x * 64;

  // stage A tile (64 rows x 128 bf16), swizzled
#pragma unroll
  for (int it = 0; it < 4; ++it) {
    int id = it * 256 + tid;            // 1024 chunks
    int row = id >> 4, c = id & 15;
    uint4 v = make_uint4(0u, 0u, 0u, 0u);
    if (base + row < N) v = *(const uint4*)&in[(base + row) * 128 + c * 8];
    *(uint4*)&lA[row * 128 + ((c ^ (row & 15)) << 3)] = v;
  }
  // stage W = wAT (128 rows x 128)
#pragma unroll
  for (int it = 0; it < 8; ++it) {
    int id = it * 256 + tid;            // 2048 chunks
    int row = id >> 4, c = id & 15;
    uint4 v = *(const uint4*)&wAT[row * 128 + c * 8];
    *(uint4*)&lW[row * 128 + ((c ^ (row & 15)) << 3)] = v;
  }
  __syncthreads();

  const int m16 = lane & 15, quad = lane >> 4;
  const int mrow = wave * 16 + m16;

  // ---- GEMM1: h1 = relu(A @ wA + bA) ----
  bf16x8 aF[4];
#pragma unroll
  for (int ks = 0; ks < 4; ++ks)
    aF[ks] = *(const bf16x8*)&lA[mrow * 128 + (((ks * 4 + quad) ^ m16) << 3)];
  f32x4 acc[8];
#pragma unroll
  for (int t = 0; t < 8; ++t) acc[t] = (f32x4){0.f, 0.f, 0.f, 0.f};
#pragma unroll
  for (int t = 0; t < 8; ++t) {
    int nrow = t * 16 + m16;
#pragma unroll
    for (int ks = 0; ks < 4; ++ks) {
      bf16x8 bF = *(const bf16x8*)&lW[nrow * 128 + (((ks * 4 + quad) ^ m16) << 3)];
      acc[t] = __builtin_amdgcn_mfma_f32_16x16x32_bf16(aF[ks], bF, acc[t], 0, 0, 0);
    }
  }
  __syncthreads();  // all GEMM1 LDS reads complete before overwriting lA/lW

  // epilogue 1: write h1 (bf16) into lA (own wave's rows only)
#pragma unroll
  for (int t = 0; t < 8; ++t) {
    int n = t * 16 + m16;
    float bias = bA[n];
#pragma unroll
    for (int r = 0; r < 4; ++r) {
      int rloc = quad * 4 + r;                 // row within wave's 16 (== absrow & 15)
      int absrow = wave * 16 + rloc;
      float v = acc[t][r] + bias;
      v = v > 0.f ? v : 0.f;
      lA[absrow * 128 + ((((n >> 3) ^ rloc) << 3) | (n & 7))] = f2bf(v);
    }
  }
  // restage W = wBT
#pragma unroll
  for (int it = 0; it < 8; ++it) {
    int id = it * 256 + tid;
    int row = id >> 4, c = id & 15;
    uint4 v = *(const uint4*)&wBT[row * 128 + c * 8];
    *(uint4*)&lW[row * 128 + ((c ^ (row & 15)) << 3)] = v;
  }
  __syncthreads();

  // ---- GEMM2: h2 = h1 @ wB + bB ----
#pragma unroll
  for (int ks = 0; ks < 4; ++ks)
    aF[ks] = *(const bf16x8*)&lA[mrow * 128 + (((ks * 4 + quad) ^ m16) << 3)];
#pragma unroll
  for (int t = 0; t < 8; ++t) acc[t] = (f32x4){0.f, 0.f, 0.f, 0.f};
#pragma unroll
  for (int t = 0; t < 8; ++t) {
    int nrow = t * 16 + m16;
#pragma unroll
    for (int ks = 0; ks < 4; ++ks) {
      bf16x8 bF = *(const bf16x8*)&lW[nrow * 128 + (((ks * 4 + quad) ^ m16) << 3)];
      acc[t] = __builtin_amdgcn_mfma_f32_16x16x32_bf16(aF[ks], bF, acc[t], 0, 0, 0);
    }
  }
  // epilogue 2: write result (bf16) into lA (own rows; own aF already consumed)
#pragma unroll
  for (int t = 0; t < 8; ++t) {
    int n = t * 16 + m16;
    float bias = bB[n];
#pragma unroll
    for (int r = 0; r < 4; ++r) {
      int rloc = quad * 4 + r;
      int absrow = wave * 16 + rloc;
      float v = acc[t][r] + bias;
      lA[absrow * 128 + ((((n >> 3) ^ rloc) << 3) | (n & 7))] = f2bf(v);
    }
  }
  __syncthreads();  // cross-wave readback below

  if (!HEAD) {
    u16* out = (u16*)outp;
    // coalesced tile store: 64 rows x 256B
#pragma unroll
    for (int it = 0; it < 4; ++it) {
      int id = it * 256 + tid;
      int row = id >> 4, c = id & 15;
      if (base + row < N) {
        uint4 v = *(const uint4*)&lA[row * 128 + ((c ^ (row & 15)) << 3)];
        *(uint4*)&out[(base + row) * 128 + c * 8] = v;
      }
    }
  } else {
    float* out = (float*)outp;
    // head: out[row] = h2b[row,:] . wo + bo ; 4 threads per row
    int row = tid >> 2, qh = tid & 3;
    float s = 0.f;
#pragma unroll
    for (int j = 0; j < 4; ++j) {
      int c = qh * 4 + j;
      uint4 v = *(const uint4*)&lA[row * 128 + ((c ^ (row & 15)) << 3)];
      const float* w = &wo[c * 8];
      float2 p;
      p = upk2(v.x); s += p.x * w[0] + p.y * w[1];
      p = upk2(v.y); s += p.x * w[2] + p.y * w[3];
      p = upk2(v.z); s += p.x * w[4] + p.y * w[5];
      p = upk2(v.w); s += p.x * w[6] + p.y * w[7];
    }
    s += __shfl_xor(s, 1, 64);
    s += __shfl_xor(s, 2, 64);
    if (qh == 0 && base + row < N) {
      out[base + row] = s + bo[0];
    }
  }
}

extern "C" void kernel_launch(void* const* d_in, const int* in_sizes, int n_in,
                              void* d_out, int out_size, void* d_ws, size_t ws_size,
                              hipStream_t stream) {
  const float* x = (const float*)d_in[0];
  const int* ei = (const int*)d_in[1];
  const int E = in_sizes[1] / 2;
  const int N = in_sizes[0] / 128;
  const int* srcI = ei;
  const int* dstI = ei + E;
  const float* w1a = (const float*)d_in[2];
  const float* b1a = (const float*)d_in[3];
  const float* w1b = (const float*)d_in[4];
  const float* b1b = (const float*)d_in[5];
  const float* w2a = (const float*)d_in[6];
  const float* b2a = (const float*)d_in[7];
  const float* w2b = (const float*)d_in[8];
  const float* b2b = (const float*)d_in[9];
  const float* wo = (const float*)d_in[10];
  const float* bo = (const float*)d_in[11];

  char* ws = (char*)d_ws;
  size_t off = 0;
  auto nx = [&](size_t bytes) {
    size_t o = off;
    off += (bytes + 511) & ~(size_t)511;
    return o;
  };
  int* cursor   = (int*)(ws + nx((size_t)N * 4));        // counts, then fill cursor
  int* rowstart = (int*)(ws + nx((size_t)(N + 1) * 4));
  int* partials = (int*)(ws + nx(4096));
  int* edge_src = (int*)(ws + nx((size_t)E * 4));
  u16* wT       = (u16*)(ws + nx((size_t)4 * 16384 * 2));
  u16* xb       = (u16*)(ws + nx((size_t)N * 128 * 2));  // bf16 x; reused as agg2 out
  u16* bufA     = (u16*)(ws + nx((size_t)N * 128 * 2));  // agg1 out
  u16* bufB     = (u16*)(ws + nx((size_t)N * 128 * 2));  // mlp1 out

  const int nb = (N + 1023) >> 10;  // scan chunks (~98)
  const int n4 = N * 32;            // N*128/4
  const int castBlocks = (n4 + 255) / 256;
  const int histBlocks = (E + 255) / 256;
  const int trBlocks = 256;

  hipMemsetAsync(cursor, 0, (size_t)N * 4, stream);
  k_prep<<<castBlocks + histBlocks + trBlocks, 256, 0, stream>>>(
      (const float4*)x, (uint2*)xb, n4, castBlocks,
      dstI, cursor, E, histBlocks,
      w1a, w1b, w2a, w2b, wT);
  k_scan1<<<nb, 256, 0, stream>>>(cursor, rowstart, partials, N);
  k_scan23<<<(N + 255) / 256, 256, 0, stream>>>(rowstart, cursor, partials, N, E, nb);
  k_fill<<<(E + 255) / 256, 256, 0, stream>>>(srcI, dstI, cursor, edge_src, E);

  const int aggBlocks = (N + 7) / 8;  // 4 waves/block, 2 nodes/wave
  k_agg<<<aggBlocks, 256, 0, stream>>>((const u32*)xb, (u32*)bufA, rowstart, edge_src, N);
  k_mlp<false><<<(N + 63) / 64, 256, 0, stream>>>(bufA, wT, b1a, wT + 16384, b1b,
                                                  nullptr, nullptr, bufB, N);
  k_agg<<<aggBlocks, 256, 0, stream>>>((const u32*)bufB, (u32*)xb, rowstart, edge_src, N);
  k_mlp<true><<<(N + 63) / 64, 256, 0, stream>>>(xb, wT + 32768, b2a, wT + 49152, b2b,
                                                 wo, bo, d_out, N);
}

// Round 6
// 258.489 us; speedup vs baseline: 1.1841x; 1.0485x over previous
//
#include <hip/hip_runtime.h>

typedef unsigned short u16;
typedef unsigned int u32;
typedef __bf16 bf16x8 __attribute__((ext_vector_type(8)));
typedef float f32x4 __attribute__((ext_vector_type(4)));

__device__ __forceinline__ u16 f2bf(float f) {
  union { float f; u32 u; } c; c.f = f;
  return (u16)((c.u + 0x7fffu + ((c.u >> 16) & 1u)) >> 16);  // RNE
}
__device__ __forceinline__ float2 upk2(u32 v) {
  union { u32 u; float f; } a, b; a.u = v << 16; b.u = v & 0xffff0000u;
  return make_float2(a.f, b.f);
}
__device__ __forceinline__ u32 pk2(float x, float y) {
  return (u32)f2bf(x) | ((u32)f2bf(y) << 16);
}

// ---------------- prep: cast (fp32->bf16) + hist + weight transpose, fused by block range ------
__global__ __launch_bounds__(256) void k_prep(const float4* __restrict__ x4,
                                              uint2* __restrict__ xb,
                                              int n4, int castBlocks,
                                              const int* __restrict__ dst,
                                              int* __restrict__ counts,
                                              int E, int histBlocks,
                                              const float* __restrict__ w0,
                                              const float* __restrict__ w1,
                                              const float* __restrict__ w2,
                                              const float* __restrict__ w3,
                                              u16* __restrict__ wT) {
  int b = blockIdx.x, t = threadIdx.x;
  if (b < castBlocks) {
    int i = b * 256 + t;
    if (i < n4) {
      float4 v = x4[i];
      xb[i] = make_uint2(pk2(v.x, v.y), pk2(v.z, v.w));
    }
  } else if (b < castBlocks + histBlocks) {
    int e = (b - castBlocks) * 256 + t;
    if (e < E) atomicAdd(&counts[dst[e]], 1);
  } else {
    int id = (b - castBlocks - histBlocks) * 256 + t;  // 0..65535
    int w = id >> 14, rem = id & 16383;
    int nn = rem >> 7, kk = rem & 127;
    const float* s = (w == 0) ? w0 : (w == 1) ? w1 : (w == 2) ? w2 : w3;
    wT[id] = f2bf(s[kk * 128 + nn]);
  }
}

// ---------------- CSR scan ----------------
__global__ __launch_bounds__(256) void k_scan1(const int* __restrict__ counts,
                                               int* __restrict__ excl,
                                               int* __restrict__ partials, int n) {
  __shared__ int sh[256];
  int b = blockIdx.x, t = threadIdx.x;
  int base = b * 1024 + t * 4;
  int v[4];
#pragma unroll
  for (int j = 0; j < 4; ++j) { int i = base + j; v[j] = (i < n) ? counts[i] : 0; }
  int tot = v[0] + v[1] + v[2] + v[3];
  sh[t] = tot; __syncthreads();
  for (int off = 1; off < 256; off <<= 1) {
    int x = (t >= off) ? sh[t - off] : 0;
    __syncthreads();
    sh[t] += x;
    __syncthreads();
  }
  int run = sh[t] - tot;  // exclusive over threads in block
#pragma unroll
  for (int j = 0; j < 4; ++j) {
    int i = base + j;
    if (i < n) excl[i] = run;
    run += v[j];
  }
  if (t == 255) partials[b] = sh[255];
}

// scan of partials (redundant per block) + apply + cursor init
__global__ __launch_bounds__(256) void k_scan23(int* __restrict__ rowstart,
                                                int* __restrict__ cursor,
                                                const int* __restrict__ partials,
                                                int n, int E, int nb) {
  __shared__ int sh[128];
  int t = threadIdx.x;
  int own = 0;
  if (t < 128) { own = (t < nb) ? partials[t] : 0; sh[t] = own; }
  __syncthreads();
  for (int off = 1; off < 128; off <<= 1) {
    int x = (t >= off && t < 128) ? sh[t - off] : 0;
    __syncthreads();
    if (t < 128) sh[t] += x;
    __syncthreads();
  }
  if (t < 128) sh[t] -= own;  // exclusive
  __syncthreads();
  int i = blockIdx.x * 256 + t;
  if (i < n) {
    int v = rowstart[i] + sh[i >> 10];
    rowstart[i] = v;
    cursor[i] = v;
  }
  if (i == 0) rowstart[n] = E;
}

__global__ __launch_bounds__(256) void k_fill(const int* __restrict__ src,
                                              const int* __restrict__ dst,
                                              int* __restrict__ cursor,
                                              int* __restrict__ edge_src, int E) {
  int e = blockIdx.x * 256 + threadIdx.x;
  if (e < E) {
    int d = dst[e];
    int pos = atomicAdd(&cursor[d], 1);
    edge_src[pos] = src[e];
  }
}

// ---------------- aggregation: out[n] = in[n] + sum_{s in nbr(n)} in[s] (bf16 io, f32 acc) --------
// One wave per node PAIR; 16 independent row-loads in flight; saturates the L2-miss path.
__global__ __launch_bounds__(256) void k_agg(const u32* __restrict__ in,
                                             u32* __restrict__ out,
                                             const int* __restrict__ rowstart,
                                             const int* __restrict__ edge_src, int N) {
  int pair = blockIdx.x * 4 + (threadIdx.x >> 6);
  int lane = threadIdx.x & 63;
  int nodeA = __builtin_amdgcn_readfirstlane(pair * 2);
  if (nodeA >= N) return;
  int nodeB = nodeA + 1;
  bool vB = nodeB < N;
  const u32* __restrict__ col = in + lane;
  float2 accA = upk2(col[(size_t)nodeA * 64]);
  float2 accB = vB ? upk2(col[(size_t)nodeB * 64]) : make_float2(0.f, 0.f);
  int a0 = rowstart[nodeA], a1 = rowstart[nodeA + 1];
  int b0 = a1, b1 = vB ? rowstart[nodeB + 1] : a1;
  int ea = a0, eb = b0;
  while (ea < a1 && eb < b1) {
    int ia[8], ib[8]; float wa[8], wb[8]; u32 va[8], vb8[8];
#pragma unroll
    for (int j = 0; j < 8; ++j) {
      int ej = ea + j; int c = (ej < a1) ? ej : (a1 - 1);
      ia[j] = edge_src[c]; wa[j] = (ej < a1) ? 1.f : 0.f;
      int fj = eb + j; int d = (fj < b1) ? fj : (b1 - 1);
      ib[j] = edge_src[d]; wb[j] = (fj < b1) ? 1.f : 0.f;
    }
#pragma unroll
    for (int j = 0; j < 8; ++j) { va[j] = col[(size_t)ia[j] * 64]; vb8[j] = col[(size_t)ib[j] * 64]; }
#pragma unroll
    for (int j = 0; j < 8; ++j) {
      float2 p = upk2(va[j]);
      accA.x = fmaf(wa[j], p.x, accA.x); accA.y = fmaf(wa[j], p.y, accA.y);
      float2 q = upk2(vb8[j]);
      accB.x = fmaf(wb[j], q.x, accB.x); accB.y = fmaf(wb[j], q.y, accB.y);
    }
    ea += 8; eb += 8;
  }
  while (ea < a1) {
    int ia[8]; float wa[8]; u32 va[8];
#pragma unroll
    for (int j = 0; j < 8; ++j) {
      int ej = ea + j; int c = (ej < a1) ? ej : (a1 - 1);
      ia[j] = edge_src[c]; wa[j] = (ej < a1) ? 1.f : 0.f;
    }
#pragma unroll
    for (int j = 0; j < 8; ++j) va[j] = col[(size_t)ia[j] * 64];
#pragma unroll
    for (int j = 0; j < 8; ++j) {
      float2 p = upk2(va[j]);
      accA.x = fmaf(wa[j], p.x, accA.x); accA.y = fmaf(wa[j], p.y, accA.y);
    }
    ea += 8;
  }
  while (eb < b1) {
    int ib[8]; float wb[8]; u32 vb8[8];
#pragma unroll
    for (int j = 0; j < 8; ++j) {
      int fj = eb + j; int d = (fj < b1) ? fj : (b1 - 1);
      ib[j] = edge_src[d]; wb[j] = (fj < b1) ? 1.f : 0.f;
    }
#pragma unroll
    for (int j = 0; j < 8; ++j) vb8[j] = col[(size_t)ib[j] * 64];
#pragma unroll
    for (int j = 0; j < 8; ++j) {
      float2 q = upk2(vb8[j]);
      accB.x = fmaf(wb[j], q.x, accB.x); accB.y = fmaf(wb[j], q.y, accB.y);
    }
    eb += 8;
  }
  out[(size_t)nodeA * 64 + lane] = pk2(accA.x, accA.y);
  if (vB) out[(size_t)nodeB * 64 + lane] = pk2(accB.x, accB.y);
}

// ---------------- persistent-weight barrier-free MLP ----------------
// Both weight matrices staged to LDS once (single __syncthreads). Then a grid-stride
// loop over 64-row tiles where each wave touches ONLY its own 16 rows of lA
// (stage, fragments, epilogues, store) -> zero barriers in the loop, waves drift
// freely, next tile's A prefetched into registers during the MFMAs.
// LDS: lA 16KB + lW 64KB = 80KB -> 2 blocks/CU.
template <bool HEAD>
__global__ __launch_bounds__(256) void k_mlp(const u16* __restrict__ in,   // [N,128] bf16
                                             const u16* __restrict__ wAT,  // [128n][128k] bf16
                                             const float* __restrict__ bA,
                                             const u16* __restrict__ wBT,
                                             const float* __restrict__ bB,
                                             const float* __restrict__ wo,  // [128] (HEAD)
                                             const float* __restrict__ bo,  // [1]   (HEAD)
                                             void* __restrict__ outp,
                                             int N, int ntiles) {
  __shared__ u16 lA[64 * 128];        // 16KB, wave w owns rows [w*16, w*16+16)
  __shared__ u16 lW[2 * 128 * 128];   // 64KB: [0]=wAT, [16384]=wBT, swizzled
  const int tid = threadIdx.x;
  const int wave = tid >> 6, lane = tid & 63;
  const int m16 = lane & 15, quad = lane >> 4;

  // stage both weight matrices (once per block)
#pragma unroll
  for (int it = 0; it < 16; ++it) {
    int id = it * 256 + tid;           // 4096 16B-chunks
    int m = id >> 11, rem = id & 2047;
    int row = rem >> 4, c = rem & 15;
    const u16* s = m ? wBT : wAT;
    uint4 v = *(const uint4*)&s[row * 128 + c * 8];
    *(uint4*)&lW[m * 16384 + row * 128 + ((c ^ (row & 15)) << 3)] = v;
  }

  // per-lane bias registers (n = t*16 + m16)
  float bAr[8], bBr[8];
#pragma unroll
  for (int t = 0; t < 8; ++t) { bAr[t] = bA[t * 16 + m16]; bBr[t] = bB[t * 16 + m16]; }
  float boV = HEAD ? bo[0] : 0.f;

  __syncthreads();  // the only barrier in this kernel

  const int mrow = wave * 16 + m16;

  uint4 pf[4];
  auto gload = [&](int tl) {
#pragma unroll
    for (int it = 0; it < 4; ++it) {
      int gr = tl * 64 + wave * 16 + it * 4 + quad;
      uint4 v = make_uint4(0u, 0u, 0u, 0u);
      if (gr < N) v = *(const uint4*)&in[(size_t)gr * 128 + m16 * 8];
      pf[it] = v;
    }
  };

  int tile = blockIdx.x;
  if (tile < ntiles) gload(tile);
  for (; tile < ntiles; tile += gridDim.x) {
    // own-wave LDS stage of this tile's A
#pragma unroll
    for (int it = 0; it < 4; ++it) {
      int row = wave * 16 + it * 4 + quad;
      *(uint4*)&lA[row * 128 + ((m16 ^ (row & 15)) << 3)] = pf[it];
    }
    // A fragments (own rows)
    bf16x8 aF[4];
#pragma unroll
    for (int ks = 0; ks < 4; ++ks)
      aF[ks] = *(const bf16x8*)&lA[mrow * 128 + (((ks * 4 + quad) ^ m16) << 3)];
    // prefetch next tile while MFMAs run
    int nxt = tile + gridDim.x;
    if (nxt < ntiles) gload(nxt);

    // ---- GEMM1 ----
    f32x4 acc[8];
#pragma unroll
    for (int t = 0; t < 8; ++t) acc[t] = (f32x4){0.f, 0.f, 0.f, 0.f};
#pragma unroll
    for (int t = 0; t < 8; ++t) {
      int nrow = t * 16 + m16;
#pragma unroll
      for (int ks = 0; ks < 4; ++ks) {
        bf16x8 bF = *(const bf16x8*)&lW[nrow * 128 + (((ks * 4 + quad) ^ m16) << 3)];
        acc[t] = __builtin_amdgcn_mfma_f32_16x16x32_bf16(aF[ks], bF, acc[t], 0, 0, 0);
      }
    }
    // epilogue 1: relu -> own rows of lA
#pragma unroll
    for (int t = 0; t < 8; ++t) {
      int n = t * 16 + m16;
#pragma unroll
      for (int r = 0; r < 4; ++r) {
        int rloc = quad * 4 + r;
        int absrow = wave * 16 + rloc;
        float v = acc[t][r] + bAr[t];
        v = v > 0.f ? v : 0.f;
        lA[absrow * 128 + ((((n >> 3) ^ rloc) << 3) | (n & 7))] = f2bf(v);
      }
    }
    // ---- GEMM2 ----
#pragma unroll
    for (int ks = 0; ks < 4; ++ks)
      aF[ks] = *(const bf16x8*)&lA[mrow * 128 + (((ks * 4 + quad) ^ m16) << 3)];
#pragma unroll
    for (int t = 0; t < 8; ++t) acc[t] = (f32x4){0.f, 0.f, 0.f, 0.f};
#pragma unroll
    for (int t = 0; t < 8; ++t) {
      int nrow = t * 16 + m16;
#pragma unroll
      for (int ks = 0; ks < 4; ++ks) {
        bf16x8 bF = *(const bf16x8*)&lW[16384 + nrow * 128 + (((ks * 4 + quad) ^ m16) << 3)];
        acc[t] = __builtin_amdgcn_mfma_f32_16x16x32_bf16(aF[ks], bF, acc[t], 0, 0, 0);
      }
    }
    if (!HEAD) {
      // epilogue 2 -> own rows of lA, then own-wave coalesced store
#pragma unroll
      for (int t = 0; t < 8; ++t) {
        int n = t * 16 + m16;
#pragma unroll
        for (int r = 0; r < 4; ++r) {
          int rloc = quad * 4 + r;
          int absrow = wave * 16 + rloc;
          float v = acc[t][r] + bBr[t];
          lA[absrow * 128 + ((((n >> 3) ^ rloc) << 3) | (n & 7))] = f2bf(v);
        }
      }
      u16* out = (u16*)outp;
#pragma unroll
      for (int it = 0; it < 4; ++it) {
        int row = wave * 16 + it * 4 + quad;
        int gr = tile * 64 + row;
        if (gr < N) {
          uint4 v = *(const uint4*)&lA[row * 128 + ((m16 ^ (row & 15)) << 3)];
          *(uint4*)&out[(size_t)gr * 128 + m16 * 8] = v;
        }
      }
    } else {
      // epilogue 2 -> own rows of lA, then per-row head dot (own wave)
#pragma unroll
      for (int t = 0; t < 8; ++t) {
        int n = t * 16 + m16;
#pragma unroll
        for (int r = 0; r < 4; ++r) {
          int rloc = quad * 4 + r;
          int absrow = wave * 16 + rloc;
          float v = acc[t][r] + bBr[t];
          lA[absrow * 128 + ((((n >> 3) ^ rloc) << 3) | (n & 7))] = f2bf(v);
        }
      }
      float* out = (float*)outp;
      int row = wave * 16 + (lane >> 2), qh = lane & 3;
      float s = 0.f;
#pragma unroll
      for (int j = 0; j < 4; ++j) {
        int c = qh * 4 + j;
        uint4 v = *(const uint4*)&lA[row * 128 + ((c ^ (row & 15)) << 3)];
        const float* w = &wo[c * 8];
        float2 p;
        p = upk2(v.x); s += p.x * w[0] + p.y * w[1];
        p = upk2(v.y); s += p.x * w[2] + p.y * w[3];
        p = upk2(v.z); s += p.x * w[4] + p.y * w[5];
        p = upk2(v.w); s += p.x * w[6] + p.y * w[7];
      }
      s += __shfl_xor(s, 1, 64);
      s += __shfl_xor(s, 2, 64);
      int gr = tile * 64 + row;
      if (qh == 0 && gr < N) out[gr] = s + boV;
    }
  }
}

extern "C" void kernel_launch(void* const* d_in, const int* in_sizes, int n_in,
                              void* d_out, int out_size, void* d_ws, size_t ws_size,
                              hipStream_t stream) {
  const float* x = (const float*)d_in[0];
  const int* ei = (const int*)d_in[1];
  const int E = in_sizes[1] / 2;
  const int N = in_sizes[0] / 128;
  const int* srcI = ei;
  const int* dstI = ei + E;
  const float* w1a = (const float*)d_in[2];
  const float* b1a = (const float*)d_in[3];
  const float* w1b = (const float*)d_in[4];
  const float* b1b = (const float*)d_in[5];
  const float* w2a = (const float*)d_in[6];
  const float* b2a = (const float*)d_in[7];
  const float* w2b = (const float*)d_in[8];
  const float* b2b = (const float*)d_in[9];
  const float* wo = (const float*)d_in[10];
  const float* bo = (const float*)d_in[11];

  char* ws = (char*)d_ws;
  size_t off = 0;
  auto nx = [&](size_t bytes) {
    size_t o = off;
    off += (bytes + 511) & ~(size_t)511;
    return o;
  };
  int* cursor   = (int*)(ws + nx((size_t)N * 4));        // counts, then fill cursor
  int* rowstart = (int*)(ws + nx((size_t)(N + 1) * 4));
  int* partials = (int*)(ws + nx(4096));
  int* edge_src = (int*)(ws + nx((size_t)E * 4));
  u16* wT       = (u16*)(ws + nx((size_t)4 * 16384 * 2));
  u16* xb       = (u16*)(ws + nx((size_t)N * 128 * 2));  // bf16 x; reused as agg2 out
  u16* bufA     = (u16*)(ws + nx((size_t)N * 128 * 2));  // agg1 out
  u16* bufB     = (u16*)(ws + nx((size_t)N * 128 * 2));  // mlp1 out

  const int nb = (N + 1023) >> 10;  // scan chunks (~98)
  const int n4 = N * 32;            // N*128/4
  const int castBlocks = (n4 + 255) / 256;
  const int histBlocks = (E + 255) / 256;
  const int trBlocks = 256;

  hipMemsetAsync(cursor, 0, (size_t)N * 4, stream);
  k_prep<<<castBlocks + histBlocks + trBlocks, 256, 0, stream>>>(
      (const float4*)x, (uint2*)xb, n4, castBlocks,
      dstI, cursor, E, histBlocks,
      w1a, w1b, w2a, w2b, wT);
  k_scan1<<<nb, 256, 0, stream>>>(cursor, rowstart, partials, N);
  k_scan23<<<(N + 255) / 256, 256, 0, stream>>>(rowstart, cursor, partials, N, E, nb);
  k_fill<<<(E + 255) / 256, 256, 0, stream>>>(srcI, dstI, cursor, edge_src, E);

  const int aggBlocks = (N + 7) / 8;  // 4 waves/block, 2 nodes/wave
  const int ntiles = (N + 63) / 64;
  const int mlpGrid = 512;            // 2 blocks/CU resident (80KB LDS)

  k_agg<<<aggBlocks, 256, 0, stream>>>((const u32*)xb, (u32*)bufA, rowstart, edge_src, N);
  k_mlp<false><<<mlpGrid, 256, 0, stream>>>(bufA, wT, b1a, wT + 16384, b1b,
                                            nullptr, nullptr, bufB, N, ntiles);
  k_agg<<<aggBlocks, 256, 0, stream>>>((const u32*)bufB, (u32*)xb, rowstart, edge_src, N);
  k_mlp<true><<<mlpGrid, 256, 0, stream>>>(xb, wT + 32768, b2a, wT + 49152, b2b,
                                           wo, bo, d_out, N, ntiles);
}

// Round 7
// 257.509 us; speedup vs baseline: 1.1886x; 1.0038x over previous
//
#include <hip/hip_runtime.h>

typedef unsigned short u16;
typedef unsigned int u32;
typedef __bf16 bf16x8 __attribute__((ext_vector_type(8)));
typedef float f32x4 __attribute__((ext_vector_type(4)));

__device__ __forceinline__ u16 f2bf(float f) {
  union { float f; u32 u; } c; c.f = f;
  return (u16)((c.u + 0x7fffu + ((c.u >> 16) & 1u)) >> 16);  // RNE
}
__device__ __forceinline__ float2 upk2(u32 v) {
  union { u32 u; float f; } a, b; a.u = v << 16; b.u = v & 0xffff0000u;
  return make_float2(a.f, b.f);
}
__device__ __forceinline__ u32 pk2(float x, float y) {
  return (u32)f2bf(x) | ((u32)f2bf(y) << 16);
}

// ---------------- prep: cast + hist + weight transpose, STRIPED so phases overlap ------
// role by blockIdx%5: slots 0-3 -> cast (BW-bound), slot 4 -> hist then tr (latency-bound).
__global__ __launch_bounds__(256) void k_prep(const float4* __restrict__ x4,
                                              uint2* __restrict__ xb,
                                              int n4,
                                              const int* __restrict__ dst,
                                              int* __restrict__ counts,
                                              int E, int histBlocks, int trBlocks,
                                              const float* __restrict__ w0,
                                              const float* __restrict__ w1,
                                              const float* __restrict__ w2,
                                              const float* __restrict__ w3,
                                              u16* __restrict__ wT) {
  int b = blockIdx.x, t = threadIdx.x;
  if ((b % 5) != 4) {
    int cb = b - b / 5;            // cast block index
    int i = cb * 256 + t;
    if (i < n4) {
      float4 v = x4[i];
      xb[i] = make_uint2(pk2(v.x, v.y), pk2(v.z, v.w));
    }
  } else {
    int k = b / 5;
    if (k < histBlocks) {
      int e = k * 256 + t;
      if (e < E) atomicAdd(&counts[dst[e]], 1);
    } else {
      int k2 = k - histBlocks;
      if (k2 < trBlocks) {
        int id = k2 * 256 + t;     // 0..65535
        int w = id >> 14, rem = id & 16383;
        int nn = rem >> 7, kk = rem & 127;
        const float* s = (w == 0) ? w0 : (w == 1) ? w1 : (w == 2) ? w2 : w3;
        wT[id] = f2bf(s[kk * 128 + nn]);
      }
    }
  }
}

// ---------------- CSR scan ----------------
__global__ __launch_bounds__(256) void k_scan1(const int* __restrict__ counts,
                                               int* __restrict__ excl,
                                               int* __restrict__ partials, int n) {
  __shared__ int sh[256];
  int b = blockIdx.x, t = threadIdx.x;
  int base = b * 1024 + t * 4;
  int v[4];
#pragma unroll
  for (int j = 0; j < 4; ++j) { int i = base + j; v[j] = (i < n) ? counts[i] : 0; }
  int tot = v[0] + v[1] + v[2] + v[3];
  sh[t] = tot; __syncthreads();
  for (int off = 1; off < 256; off <<= 1) {
    int x = (t >= off) ? sh[t - off] : 0;
    __syncthreads();
    sh[t] += x;
    __syncthreads();
  }
  int run = sh[t] - tot;  // exclusive over threads in block
#pragma unroll
  for (int j = 0; j < 4; ++j) {
    int i = base + j;
    if (i < n) excl[i] = run;
    run += v[j];
  }
  if (t == 255) partials[b] = sh[255];
}

// scan of partials (redundant per block) + apply + cursor init
__global__ __launch_bounds__(256) void k_scan23(int* __restrict__ rowstart,
                                                int* __restrict__ cursor,
                                                const int* __restrict__ partials,
                                                int n, int E, int nb) {
  __shared__ int sh[128];
  int t = threadIdx.x;
  int own = 0;
  if (t < 128) { own = (t < nb) ? partials[t] : 0; sh[t] = own; }
  __syncthreads();
  for (int off = 1; off < 128; off <<= 1) {
    int x = (t >= off && t < 128) ? sh[t - off] : 0;
    __syncthreads();
    if (t < 128) sh[t] += x;
    __syncthreads();
  }
  if (t < 128) sh[t] -= own;  // exclusive
  __syncthreads();
  int i = blockIdx.x * 256 + t;
  if (i < n) {
    int v = rowstart[i] + sh[i >> 10];
    rowstart[i] = v;
    cursor[i] = v;
  }
  if (i == 0) rowstart[n] = E;
}

__global__ __launch_bounds__(256) void k_fill(const int* __restrict__ src,
                                              const int* __restrict__ dst,
                                              int* __restrict__ cursor,
                                              int* __restrict__ edge_src, int E) {
  int e = blockIdx.x * 256 + threadIdx.x;
  if (e < E) {
    int d = dst[e];
    int pos = atomicAdd(&cursor[d], 1);
    edge_src[pos] = src[e];
  }
}

// ---------------- aggregation: out[n] = in[n] + sum_{s in nbr(n)} in[s] (bf16 io, f32 acc) --------
// One wave per node PAIR; 16 independent row-loads in flight; saturates the random-gather path.
__global__ __launch_bounds__(256) void k_agg(const u32* __restrict__ in,
                                             u32* __restrict__ out,
                                             const int* __restrict__ rowstart,
                                             const int* __restrict__ edge_src, int N) {
  int pair = blockIdx.x * 4 + (threadIdx.x >> 6);
  int lane = threadIdx.x & 63;
  int nodeA = __builtin_amdgcn_readfirstlane(pair * 2);
  if (nodeA >= N) return;
  int nodeB = nodeA + 1;
  bool vB = nodeB < N;
  const u32* __restrict__ col = in + lane;
  float2 accA = upk2(col[(size_t)nodeA * 64]);
  float2 accB = vB ? upk2(col[(size_t)nodeB * 64]) : make_float2(0.f, 0.f);
  int a0 = rowstart[nodeA], a1 = rowstart[nodeA + 1];
  int b0 = a1, b1 = vB ? rowstart[nodeB + 1] : a1;
  int ea = a0, eb = b0;
  while (ea < a1 && eb < b1) {
    int ia[8], ib[8]; float wa[8], wb[8]; u32 va[8], vb8[8];
#pragma unroll
    for (int j = 0; j < 8; ++j) {
      int ej = ea + j; int c = (ej < a1) ? ej : (a1 - 1);
      ia[j] = edge_src[c]; wa[j] = (ej < a1) ? 1.f : 0.f;
      int fj = eb + j; int d = (fj < b1) ? fj : (b1 - 1);
      ib[j] = edge_src[d]; wb[j] = (fj < b1) ? 1.f : 0.f;
    }
#pragma unroll
    for (int j = 0; j < 8; ++j) { va[j] = col[(size_t)ia[j] * 64]; vb8[j] = col[(size_t)ib[j] * 64]; }
#pragma unroll
    for (int j = 0; j < 8; ++j) {
      float2 p = upk2(va[j]);
      accA.x = fmaf(wa[j], p.x, accA.x); accA.y = fmaf(wa[j], p.y, accA.y);
      float2 q = upk2(vb8[j]);
      accB.x = fmaf(wb[j], q.x, accB.x); accB.y = fmaf(wb[j], q.y, accB.y);
    }
    ea += 8; eb += 8;
  }
  while (ea < a1) {
    int ia[8]; float wa[8]; u32 va[8];
#pragma unroll
    for (int j = 0; j < 8; ++j) {
      int ej = ea + j; int c = (ej < a1) ? ej : (a1 - 1);
      ia[j] = edge_src[c]; wa[j] = (ej < a1) ? 1.f : 0.f;
    }
#pragma unroll
    for (int j = 0; j < 8; ++j) va[j] = col[(size_t)ia[j] * 64];
#pragma unroll
    for (int j = 0; j < 8; ++j) {
      float2 p = upk2(va[j]);
      accA.x = fmaf(wa[j], p.x, accA.x); accA.y = fmaf(wa[j], p.y, accA.y);
    }
    ea += 8;
  }
  while (eb < b1) {
    int ib[8]; float wb[8]; u32 vb8[8];
#pragma unroll
    for (int j = 0; j < 8; ++j) {
      int fj = eb + j; int d = (fj < b1) ? fj : (b1 - 1);
      ib[j] = edge_src[d]; wb[j] = (fj < b1) ? 1.f : 0.f;
    }
#pragma unroll
    for (int j = 0; j < 8; ++j) vb8[j] = col[(size_t)ib[j] * 64];
#pragma unroll
    for (int j = 0; j < 8; ++j) {
      float2 q = upk2(vb8[j]);
      accB.x = fmaf(wb[j], q.x, accB.x); accB.y = fmaf(wb[j], q.y, accB.y);
    }
    eb += 8;
  }
  out[(size_t)nodeA * 64 + lane] = pk2(accA.x, accA.y);
  if (vB) out[(size_t)nodeB * 64 + lane] = pk2(accB.x, accB.y);
}

// ---------------- persistent-weight barrier-free MLP ----------------
// Both weight matrices staged to LDS once (single __syncthreads). Grid-stride loop over
// 64-row tiles; each wave touches only its own 16 rows of lA -> zero barriers in the loop.
// HEAD: head dot computed straight from GEMM2 accumulators (no LDS round-trip):
//   lane(m16,quad) holds C[row=quad*4+r][col=t*16+m16] -> s[r]=sum_t acc[t][r]*wo[t*16+m16],
//   then butterfly shfl_xor over the 4 m16 bits.
template <bool HEAD>
__global__ __launch_bounds__(256) void k_mlp(const u16* __restrict__ in,   // [N,128] bf16
                                             const u16* __restrict__ wAT,  // [128n][128k] bf16
                                             const float* __restrict__ bA,
                                             const u16* __restrict__ wBT,
                                             const float* __restrict__ bB,
                                             const float* __restrict__ wo,  // [128] (HEAD)
                                             const float* __restrict__ bo,  // [1]   (HEAD)
                                             void* __restrict__ outp,
                                             int N, int ntiles) {
  __shared__ u16 lA[64 * 128];        // 16KB, wave w owns rows [w*16, w*16+16)
  __shared__ u16 lW[2 * 128 * 128];   // 64KB: [0]=wAT, [16384]=wBT, swizzled
  const int tid = threadIdx.x;
  const int wave = tid >> 6, lane = tid & 63;
  const int m16 = lane & 15, quad = lane >> 4;

  // stage both weight matrices (once per block)
#pragma unroll
  for (int it = 0; it < 16; ++it) {
    int id = it * 256 + tid;           // 4096 16B-chunks
    int m = id >> 11, rem = id & 2047;
    int row = rem >> 4, c = rem & 15;
    const u16* s = m ? wBT : wAT;
    uint4 v = *(const uint4*)&s[row * 128 + c * 8];
    *(uint4*)&lW[m * 16384 + row * 128 + ((c ^ (row & 15)) << 3)] = v;
  }

  // per-lane bias / head-weight registers (n = t*16 + m16)
  float bAr[8], bBr[8], woR[8];
#pragma unroll
  for (int t = 0; t < 8; ++t) {
    bAr[t] = bA[t * 16 + m16];
    bBr[t] = HEAD ? 0.f : bB[t * 16 + m16];
    woR[t] = HEAD ? wo[t * 16 + m16] : 0.f;
  }
  float bBh[8];
#pragma unroll
  for (int t = 0; t < 8; ++t) bBh[t] = HEAD ? bB[t * 16 + m16] : 0.f;
  float boV = HEAD ? bo[0] : 0.f;

  __syncthreads();  // the only barrier in this kernel

  const int mrow = wave * 16 + m16;

  uint4 pf[4];
  auto gload = [&](int tl) {
#pragma unroll
    for (int it = 0; it < 4; ++it) {
      int gr = tl * 64 + wave * 16 + it * 4 + quad;
      uint4 v = make_uint4(0u, 0u, 0u, 0u);
      if (gr < N) v = *(const uint4*)&in[(size_t)gr * 128 + m16 * 8];
      pf[it] = v;
    }
  };

  int tile = blockIdx.x;
  if (tile < ntiles) gload(tile);
  for (; tile < ntiles; tile += gridDim.x) {
    // own-wave LDS stage of this tile's A
#pragma unroll
    for (int it = 0; it < 4; ++it) {
      int row = wave * 16 + it * 4 + quad;
      *(uint4*)&lA[row * 128 + ((m16 ^ (row & 15)) << 3)] = pf[it];
    }
    // A fragments (own rows)
    bf16x8 aF[4];
#pragma unroll
    for (int ks = 0; ks < 4; ++ks)
      aF[ks] = *(const bf16x8*)&lA[mrow * 128 + (((ks * 4 + quad) ^ m16) << 3)];
    // prefetch next tile while MFMAs run
    int nxt = tile + gridDim.x;
    if (nxt < ntiles) gload(nxt);

    // ---- GEMM1 ----
    f32x4 acc[8];
#pragma unroll
    for (int t = 0; t < 8; ++t) acc[t] = (f32x4){0.f, 0.f, 0.f, 0.f};
#pragma unroll
    for (int t = 0; t < 8; ++t) {
      int nrow = t * 16 + m16;
#pragma unroll
      for (int ks = 0; ks < 4; ++ks) {
        bf16x8 bF = *(const bf16x8*)&lW[nrow * 128 + (((ks * 4 + quad) ^ m16) << 3)];
        acc[t] = __builtin_amdgcn_mfma_f32_16x16x32_bf16(aF[ks], bF, acc[t], 0, 0, 0);
      }
    }
    // epilogue 1: relu -> own rows of lA
#pragma unroll
    for (int t = 0; t < 8; ++t) {
      int n = t * 16 + m16;
#pragma unroll
      for (int r = 0; r < 4; ++r) {
        int rloc = quad * 4 + r;
        int absrow = wave * 16 + rloc;
        float v = acc[t][r] + bAr[t];
        v = v > 0.f ? v : 0.f;
        lA[absrow * 128 + ((((n >> 3) ^ rloc) << 3) | (n & 7))] = f2bf(v);
      }
    }
    // ---- GEMM2 ----
#pragma unroll
    for (int ks = 0; ks < 4; ++ks)
      aF[ks] = *(const bf16x8*)&lA[mrow * 128 + (((ks * 4 + quad) ^ m16) << 3)];
#pragma unroll
    for (int t = 0; t < 8; ++t) acc[t] = (f32x4){0.f, 0.f, 0.f, 0.f};
#pragma unroll
    for (int t = 0; t < 8; ++t) {
      int nrow = t * 16 + m16;
#pragma unroll
      for (int ks = 0; ks < 4; ++ks) {
        bf16x8 bF = *(const bf16x8*)&lW[16384 + nrow * 128 + (((ks * 4 + quad) ^ m16) << 3)];
        acc[t] = __builtin_amdgcn_mfma_f32_16x16x32_bf16(aF[ks], bF, acc[t], 0, 0, 0);
      }
    }
    if (!HEAD) {
      // epilogue 2 -> own rows of lA, then own-wave coalesced store
#pragma unroll
      for (int t = 0; t < 8; ++t) {
        int n = t * 16 + m16;
#pragma unroll
        for (int r = 0; r < 4; ++r) {
          int rloc = quad * 4 + r;
          int absrow = wave * 16 + rloc;
          float v = acc[t][r] + bBr[t];
          lA[absrow * 128 + ((((n >> 3) ^ rloc) << 3) | (n & 7))] = f2bf(v);
        }
      }
      u16* out = (u16*)outp;
#pragma unroll
      for (int it = 0; it < 4; ++it) {
        int row = wave * 16 + it * 4 + quad;
        int gr = tile * 64 + row;
        if (gr < N) {
          uint4 v = *(const uint4*)&lA[row * 128 + ((m16 ^ (row & 15)) << 3)];
          *(uint4*)&out[(size_t)gr * 128 + m16 * 8] = v;
        }
      }
    } else {
      // head straight from accumulators: s[r] = sum_t (acc[t][r] + bB[col]) * wo[col]
      float* out = (float*)outp;
      float s[4];
#pragma unroll
      for (int r = 0; r < 4; ++r) {
        float v = 0.f;
#pragma unroll
        for (int t = 0; t < 8; ++t) v += (acc[t][r] + bBh[t]) * woR[t];
        s[r] = v;
      }
#pragma unroll
      for (int r = 0; r < 4; ++r) {
        s[r] += __shfl_xor(s[r], 1, 64);
        s[r] += __shfl_xor(s[r], 2, 64);
        s[r] += __shfl_xor(s[r], 4, 64);
        s[r] += __shfl_xor(s[r], 8, 64);
      }
      if (m16 == 0) {
#pragma unroll
        for (int r = 0; r < 4; ++r) {
          int gr = tile * 64 + wave * 16 + quad * 4 + r;
          if (gr < N) out[gr] = s[r] + boV;
        }
      }
    }
  }
}

extern "C" void kernel_launch(void* const* d_in, const int* in_sizes, int n_in,
                              void* d_out, int out_size, void* d_ws, size_t ws_size,
                              hipStream_t stream) {
  const float* x = (const float*)d_in[0];
  const int* ei = (const int*)d_in[1];
  const int E = in_sizes[1] / 2;
  const int N = in_sizes[0] / 128;
  const int* srcI = ei;
  const int* dstI = ei + E;
  const float* w1a = (const float*)d_in[2];
  const float* b1a = (const float*)d_in[3];
  const float* w1b = (const float*)d_in[4];
  const float* b1b = (const float*)d_in[5];
  const float* w2a = (const float*)d_in[6];
  const float* b2a = (const float*)d_in[7];
  const float* w2b = (const float*)d_in[8];
  const float* b2b = (const float*)d_in[9];
  const float* wo = (const float*)d_in[10];
  const float* bo = (const float*)d_in[11];

  char* ws = (char*)d_ws;
  size_t off = 0;
  auto nx = [&](size_t bytes) {
    size_t o = off;
    off += (bytes + 511) & ~(size_t)511;
    return o;
  };
  int* cursor   = (int*)(ws + nx((size_t)N * 4));        // counts, then fill cursor
  int* rowstart = (int*)(ws + nx((size_t)(N + 1) * 4));
  int* partials = (int*)(ws + nx(4096));
  int* edge_src = (int*)(ws + nx((size_t)E * 4));
  u16* wT       = (u16*)(ws + nx((size_t)4 * 16384 * 2));
  u16* xb       = (u16*)(ws + nx((size_t)N * 128 * 2));  // bf16 x; reused as agg2 out
  u16* bufA     = (u16*)(ws + nx((size_t)N * 128 * 2));  // agg1 out
  u16* bufB     = (u16*)(ws + nx((size_t)N * 128 * 2));  // mlp1 out

  const int nb = (N + 1023) >> 10;  // scan chunks (~98)
  const int n4 = N * 32;            // N*128/4
  const int castBlocks = (n4 + 255) / 256;
  const int histBlocks = (E + 255) / 256;
  const int trBlocks = 256;

  // grid G: cast slots (b%5 != 4) must cover castBlocks; other slots (b%5==4) must
  // cover histBlocks + trBlocks. Guards make slack safe.
  int G = (castBlocks * 5 + 3) / 4 + 4;
  if (G < 5 * (histBlocks + trBlocks)) G = 5 * (histBlocks + trBlocks);

  hipMemsetAsync(cursor, 0, (size_t)N * 4, stream);
  k_prep<<<G, 256, 0, stream>>>((const float4*)x, (uint2*)xb, n4,
                                dstI, cursor, E, histBlocks, trBlocks,
                                w1a, w1b, w2a, w2b, wT);
  k_scan1<<<nb, 256, 0, stream>>>(cursor, rowstart, partials, N);
  k_scan23<<<(N + 255) / 256, 256, 0, stream>>>(rowstart, cursor, partials, N, E, nb);
  k_fill<<<(E + 255) / 256, 256, 0, stream>>>(srcI, dstI, cursor, edge_src, E);

  const int aggBlocks = (N + 7) / 8;  // 4 waves/block, 2 nodes/wave
  const int ntiles = (N + 63) / 64;
  const int mlpGrid = 512;            // 2 blocks/CU resident (80KB LDS)

  k_agg<<<aggBlocks, 256, 0, stream>>>((const u32*)xb, (u32*)bufA, rowstart, edge_src, N);
  k_mlp<false><<<mlpGrid, 256, 0, stream>>>(bufA, wT, b1a, wT + 16384, b1b,
                                            nullptr, nullptr, bufB, N, ntiles);
  k_agg<<<aggBlocks, 256, 0, stream>>>((const u32*)bufB, (u32*)xb, rowstart, edge_src, N);
  k_mlp<true><<<mlpGrid, 256, 0, stream>>>(xb, wT + 32768, b2a, wT + 49152, b2b,
                                           wo, bo, d_out, N, ntiles);
}